// Round 18
// baseline (294.963 us; speedup 1.0000x reference)
//
#include <hip/hip_runtime.h>

#define HID   256
#define BATCH 8
#define TT    256   // time steps (SEQ-1)
#define SEQL  257
#define VOCAB 29
#define EMB   64
#define TG    4     // attn t-tile
#define CH    8     // pipeline chunk (steps)
#define NCHK  (TT / CH)

typedef _Float16 f16;
typedef f16  f16x8 __attribute__((ext_vector_type(8)));
typedef float f32x4 __attribute__((ext_vector_type(4)));

__device__ int g_flags[48];   // [0..7]=A pairs, [8..15]=B pairs, [16..23]=C pairs,
                              // [24..31]=D pairs, [32..39]=E pairs (re-zeroed each call)

__device__ __forceinline__ float fast_tanh(float x) {
    float e = exp2f(x * 2.8853900817779268f);
    return 1.0f - 2.0f * __builtin_amdgcn_rcpf(1.0f + e);
}

// C0[t][b][i] = emb[x[b][t]] . W_ih0[i] + b_ih0[i] + b_hh0[i]; zero g_flags.
__global__ __launch_bounds__(256) void pre0_kernel(
    const int* __restrict__ x, const float* __restrict__ embed,
    const float* __restrict__ Wih0, const float* __restrict__ bih0,
    const float* __restrict__ bhh0, float* __restrict__ C0)
{
    if (blockIdx.x == 0 && threadIdx.x < 48) g_flags[threadIdx.x] = 0;
    int b  = blockIdx.x & 7;
    int t0 = (blockIdx.x >> 3) * 8;
    int tid = threadIdx.x;
    __shared__ float er[8][EMB];
    for (int idx = tid; idx < 8 * EMB; idx += 256) {
        int tt = idx >> 6, j = idx & 63;
        er[tt][j] = embed[x[b * SEQL + t0 + tt] * EMB + j];
    }
    __syncthreads();
    int i = tid;
    float base = bih0[i] + bhh0[i];
    float acc[8];
#pragma unroll
    for (int tt = 0; tt < 8; ++tt) acc[tt] = base;
    const float* wr = Wih0 + i * EMB;
    for (int j = 0; j < EMB; j += 4) {
        float4 w = *(const float4*)&wr[j];
#pragma unroll
        for (int tt = 0; tt < 8; ++tt) {
            float4 h = *(const float4*)&er[tt][j];
            acc[tt] += h.x * w.x + h.y * w.y + h.z * w.z + h.w * w.w;
        }
    }
#pragma unroll
    for (int tt = 0; tt < 8; ++tt)
        C0[((t0 + tt) * BATCH + b) * HID + i] = acc[tt];
}

struct SmemM { f16 hbuf[2][HID]; __align__(16) f16 stg[CH][HID]; };
struct SmemA { float qs[TG][HID]; float vs[HID]; float alpha[TG][HID];
               float cvec[TG][8][68]; float redm[4][TG]; float reds[4][TG]; };
union SmemU { SmemM m; SmemA a; };

// Unified pipeline + attention. Grid 552x512:
//  blocks 0-7  (A): layer0 rec, ungated; posts g_flags[b] per pair
//  blocks 8-15 (B): C1 producer, 2 chunks/wait; posts [8+b] per pair
//  blocks 16-23(C): layer1 rec, 2 chunks/wait; posts [16+b] per pair
//  blocks 24-31(D): tq, 2 chunks/wait; posts [24+b] per pair
//  blocks 32-39(E): tkT, 2 chunks/wait; posts [32+b] per pair
//  blocks 40-551: one attn tile (b,t0) each; waits D&E pair ceil((t0+TG)/16)
__global__ __launch_bounds__(512) void mega_kernel(
    const float* __restrict__ Whh0, const float* __restrict__ Wih1,
    const float* __restrict__ Whh1, const float* __restrict__ bih1,
    const float* __restrict__ bhh1, const float* __restrict__ Wq,
    const float* __restrict__ Wk, const float* __restrict__ C0,
    float* __restrict__ Q, float* __restrict__ Hs, float* __restrict__ tkT,
    const float* __restrict__ vvec, const float* __restrict__ Wfc,
    const float* __restrict__ bfc, float* __restrict__ out)
{
    __shared__ SmemU smem;
    int tid = threadIdx.x;
    int wave = tid >> 6, lane = tid & 63;
    int lrow = lane & 15, lkg = lane >> 4;
    int role = (blockIdx.x < 40) ? (blockIdx.x >> 3) : 5;
    int b = blockIdx.x & 7;
    int i0 = wave * 32 + lrow, i1 = i0 + 16;
    const f32x4 Z = {0.f, 0.f, 0.f, 0.f};

#define WAITF(idx, val)                                                             \
    {                                                                               \
        if (tid == 0) {                                                             \
            while (__hip_atomic_load(&g_flags[idx], __ATOMIC_ACQUIRE,               \
                                     __HIP_MEMORY_SCOPE_AGENT) < (val))             \
                __builtin_amdgcn_s_sleep(2);                                        \
        }                                                                           \
        __syncthreads();                                                            \
    }
#define POSTF(idx, val)                                                             \
    {                                                                               \
        __syncthreads();                                                            \
        if (tid == 0) {                                                             \
            __hip_atomic_store(&g_flags[idx], (val), __ATOMIC_RELEASE,              \
                               __HIP_MEMORY_SCOPE_AGENT);                           \
        }                                                                           \
    }

    f16x8 a[8];
#pragma unroll
    for (int kt = 0; kt < 8; ++kt)
#pragma unroll
        for (int e = 0; e < 8; ++e) a[kt][e] = (f16)0.f;

    if (role == 0) {
        // ---------------- A: layer 0 rec (ungated) ----------------
        f16 (*hbuf)[HID] = smem.m.hbuf;
        for (int idx = tid; idx < 2 * HID; idx += 512) ((f16*)hbuf)[idx] = (f16)0.f;
        f16x8 bf[8][2];
#pragma unroll
        for (int kt = 0; kt < 8; ++kt)
#pragma unroll
            for (int ct = 0; ct < 2; ++ct) {
                int n = wave * 32 + ct * 16 + lrow;
                const float* src = Whh0 + n * HID + kt * 32 + lkg * 8;
                f16x8 v;
#pragma unroll
                for (int e = 0; e < 8; ++e) v[e] = (f16)src[e];
                bf[kt][ct] = v;
            }
        __syncthreads();
        const float* cp = C0 + b * HID;
        float c0 = cp[i0], c1 = cp[i1];
        cp += BATCH * HID;
        f16* hp = (f16*)(Q + (size_t)b * TT * HID);

#define ASTEP(CUR, NXT)                                                             \
    {                                                                               \
        float cn0 = cp[i0];                                                         \
        float cn1 = cp[i1];                                                         \
        cp += BATCH * HID;                                                          \
        if (lrow == 0) {                                                            \
            _Pragma("unroll")                                                       \
            for (int kt = 0; kt < 8; ++kt)                                          \
                a[kt] = *(const f16x8*)&hbuf[CUR][kt * 32 + lkg * 8];               \
        }                                                                           \
        f32x4 p00 = __builtin_amdgcn_mfma_f32_16x16x32_f16(a[0], bf[0][0], Z, 0, 0, 0); \
        f32x4 p01 = __builtin_amdgcn_mfma_f32_16x16x32_f16(a[0], bf[0][1], Z, 0, 0, 0); \
        f32x4 p10 = __builtin_amdgcn_mfma_f32_16x16x32_f16(a[2], bf[2][0], Z, 0, 0, 0); \
        f32x4 p11 = __builtin_amdgcn_mfma_f32_16x16x32_f16(a[2], bf[2][1], Z, 0, 0, 0); \
        f32x4 p20 = __builtin_amdgcn_mfma_f32_16x16x32_f16(a[4], bf[4][0], Z, 0, 0, 0); \
        f32x4 p21 = __builtin_amdgcn_mfma_f32_16x16x32_f16(a[4], bf[4][1], Z, 0, 0, 0); \
        f32x4 p30 = __builtin_amdgcn_mfma_f32_16x16x32_f16(a[6], bf[6][0], Z, 0, 0, 0); \
        f32x4 p31 = __builtin_amdgcn_mfma_f32_16x16x32_f16(a[6], bf[6][1], Z, 0, 0, 0); \
        p00 = __builtin_amdgcn_mfma_f32_16x16x32_f16(a[1], bf[1][0], p00, 0, 0, 0); \
        p01 = __builtin_amdgcn_mfma_f32_16x16x32_f16(a[1], bf[1][1], p01, 0, 0, 0); \
        p10 = __builtin_amdgcn_mfma_f32_16x16x32_f16(a[3], bf[3][0], p10, 0, 0, 0); \
        p11 = __builtin_amdgcn_mfma_f32_16x16x32_f16(a[3], bf[3][1], p11, 0, 0, 0); \
        p20 = __builtin_amdgcn_mfma_f32_16x16x32_f16(a[5], bf[5][0], p20, 0, 0, 0); \
        p21 = __builtin_amdgcn_mfma_f32_16x16x32_f16(a[5], bf[5][1], p21, 0, 0, 0); \
        p30 = __builtin_amdgcn_mfma_f32_16x16x32_f16(a[7], bf[7][0], p30, 0, 0, 0); \
        p31 = __builtin_amdgcn_mfma_f32_16x16x32_f16(a[7], bf[7][1], p31, 0, 0, 0); \
        float v0 = fast_tanh(((p00[0] + p10[0]) + (p20[0] + p30[0])) + c0);         \
        float v1 = fast_tanh(((p01[0] + p11[0]) + (p21[0] + p31[0])) + c1);         \
        f16 hv0 = (f16)v0, hv1 = (f16)v1;                                           \
        if (lane < 16) {                                                            \
            hbuf[NXT][i0] = hv0;                                                    \
            hbuf[NXT][i1] = hv1;                                                    \
            hp[i0] = hv0;                                                           \
            hp[i1] = hv1;                                                           \
        }                                                                           \
        hp += 2 * HID;   /* STRIDE 2*HID: keeps h0[t] clear of B's C1 overwrites */ \
        c0 = cn0; c1 = cn1;                                                         \
        asm volatile("s_waitcnt lgkmcnt(0)\n\ts_barrier" ::: "memory");             \
    }

        for (int ch = 0; ch < NCHK; ++ch) {
            ASTEP(0, 1) ASTEP(1, 0) ASTEP(0, 1) ASTEP(1, 0)
            ASTEP(0, 1) ASTEP(1, 0) ASTEP(0, 1) ASTEP(1, 0)
            if (ch & 1) POSTF(b, (ch + 1) >> 1)
        }
#undef ASTEP
    } else if (role == 1) {
        // ---------------- B: C1 producer, 2 chunks per wait ----------------
        f16 (*stg)[HID] = smem.m.stg;
        f16x8 bfI[8][2];
#pragma unroll
        for (int kt = 0; kt < 8; ++kt)
#pragma unroll
            for (int ct = 0; ct < 2; ++ct) {
                int n = wave * 32 + ct * 16 + lrow;
                const float* src = Wih1 + n * HID + kt * 32 + lkg * 8;
                f16x8 v;
#pragma unroll
                for (int e = 0; e < 8; ++e) v[e] = (f16)src[e];
                bfI[kt][ct] = v;
            }
        int col0 = wave * 32 + (lane & 15), col1 = col0 + 16;
        float bv0 = bih1[col0] + bhh1[col0];
        float bv1 = bih1[col1] + bhh1[col1];
        float* qb = Q + (size_t)b * TT * HID;

#define BBODY(CH_IDX)                                                               \
    {                                                                               \
        int ch = (CH_IDX);                                                          \
        if (tid < 256) {                                                            \
            int tp = tid >> 5, seg = tid & 31;                                      \
            *(f16x8*)&stg[tp][seg * 8] =                                            \
                *(const f16x8*)((const f16*)(qb + (size_t)(ch * CH + tp) * HID) + seg * 8); \
        }                                                                           \
        __syncthreads();                                                            \
        if (lrow < 8) {                                                             \
            _Pragma("unroll")                                                       \
            for (int kt = 0; kt < 8; ++kt)                                          \
                a[kt] = *(const f16x8*)&stg[lrow][kt * 32 + lkg * 8];               \
        }                                                                           \
        f32x4 u0 = __builtin_amdgcn_mfma_f32_16x16x32_f16(a[0], bfI[0][0], Z, 0, 0, 0); \
        f32x4 u1 = __builtin_amdgcn_mfma_f32_16x16x32_f16(a[0], bfI[0][1], Z, 0, 0, 0); \
        _Pragma("unroll")                                                           \
        for (int kt = 1; kt < 8; ++kt) {                                            \
            u0 = __builtin_amdgcn_mfma_f32_16x16x32_f16(a[kt], bfI[kt][0], u0, 0, 0, 0); \
            u1 = __builtin_amdgcn_mfma_f32_16x16x32_f16(a[kt], bfI[kt][1], u1, 0, 0, 0); \
        }                                                                           \
        if (lane < 32) {                                                            \
            float* co = qb + (size_t)(ch * CH + (lane >> 4) * 4) * HID;             \
            co[0 * HID + col0] = u0[0] + bv0;                                       \
            co[1 * HID + col0] = u0[1] + bv0;                                       \
            co[2 * HID + col0] = u0[2] + bv0;                                       \
            co[3 * HID + col0] = u0[3] + bv0;                                       \
            co[0 * HID + col1] = u1[0] + bv1;                                       \
            co[1 * HID + col1] = u1[1] + bv1;                                       \
            co[2 * HID + col1] = u1[2] + bv1;                                       \
            co[3 * HID + col1] = u1[3] + bv1;                                       \
        }                                                                           \
    }

        for (int chp = 0; chp < NCHK / 2; ++chp) {
            WAITF(b, chp + 1)
            BBODY(2 * chp)
            __syncthreads();
            BBODY(2 * chp + 1)
            POSTF(8 + b, chp + 1)
        }
#undef BBODY
    } else if (role == 2) {
        // ---------------- C: layer 1 rec, 2 chunks per wait ----------------
        f16 (*hbuf)[HID] = smem.m.hbuf;
        for (int idx = tid; idx < 2 * HID; idx += 512) ((f16*)hbuf)[idx] = (f16)0.f;
        f16x8 bf[8][2];
#pragma unroll
        for (int kt = 0; kt < 8; ++kt)
#pragma unroll
            for (int ct = 0; ct < 2; ++ct) {
                int n = wave * 32 + ct * 16 + lrow;
                const float* src = Whh1 + n * HID + kt * 32 + lkg * 8;
                f16x8 v;
#pragma unroll
                for (int e = 0; e < 8; ++e) v[e] = (f16)src[e];
                bf[kt][ct] = v;
            }
        __syncthreads();
        float* ho = Hs + (size_t)b * TT * HID;
        const float* cq = Q + (size_t)b * TT * HID;

#define CSTEP(CUR, NXT, CV0, CV1)                                                   \
    {                                                                               \
        if (lrow == 0) {                                                            \
            _Pragma("unroll")                                                       \
            for (int kt = 0; kt < 8; ++kt)                                          \
                a[kt] = *(const f16x8*)&hbuf[CUR][kt * 32 + lkg * 8];               \
        }                                                                           \
        f32x4 p00 = __builtin_amdgcn_mfma_f32_16x16x32_f16(a[0], bf[0][0], Z, 0, 0, 0); \
        f32x4 p01 = __builtin_amdgcn_mfma_f32_16x16x32_f16(a[0], bf[0][1], Z, 0, 0, 0); \
        f32x4 p10 = __builtin_amdgcn_mfma_f32_16x16x32_f16(a[2], bf[2][0], Z, 0, 0, 0); \
        f32x4 p11 = __builtin_amdgcn_mfma_f32_16x16x32_f16(a[2], bf[2][1], Z, 0, 0, 0); \
        f32x4 p20 = __builtin_amdgcn_mfma_f32_16x16x32_f16(a[4], bf[4][0], Z, 0, 0, 0); \
        f32x4 p21 = __builtin_amdgcn_mfma_f32_16x16x32_f16(a[4], bf[4][1], Z, 0, 0, 0); \
        f32x4 p30 = __builtin_amdgcn_mfma_f32_16x16x32_f16(a[6], bf[6][0], Z, 0, 0, 0); \
        f32x4 p31 = __builtin_amdgcn_mfma_f32_16x16x32_f16(a[6], bf[6][1], Z, 0, 0, 0); \
        p00 = __builtin_amdgcn_mfma_f32_16x16x32_f16(a[1], bf[1][0], p00, 0, 0, 0); \
        p01 = __builtin_amdgcn_mfma_f32_16x16x32_f16(a[1], bf[1][1], p01, 0, 0, 0); \
        p10 = __builtin_amdgcn_mfma_f32_16x16x32_f16(a[3], bf[3][0], p10, 0, 0, 0); \
        p11 = __builtin_amdgcn_mfma_f32_16x16x32_f16(a[3], bf[3][1], p11, 0, 0, 0); \
        p20 = __builtin_amdgcn_mfma_f32_16x16x32_f16(a[5], bf[5][0], p20, 0, 0, 0); \
        p21 = __builtin_amdgcn_mfma_f32_16x16x32_f16(a[5], bf[5][1], p21, 0, 0, 0); \
        p30 = __builtin_amdgcn_mfma_f32_16x16x32_f16(a[7], bf[7][0], p30, 0, 0, 0); \
        p31 = __builtin_amdgcn_mfma_f32_16x16x32_f16(a[7], bf[7][1], p31, 0, 0, 0); \
        float v0 = fast_tanh(((p00[0] + p10[0]) + (p20[0] + p30[0])) + CV0);        \
        float v1 = fast_tanh(((p01[0] + p11[0]) + (p21[0] + p31[0])) + CV1);        \
        if (lane < 16) {                                                            \
            hbuf[NXT][i0] = (f16)v0;                                                \
            hbuf[NXT][i1] = (f16)v1;                                                \
            ho[i0] = v0;                                                            \
            ho[i1] = v1;                                                            \
        }                                                                           \
        ho += HID;                                                                  \
        asm volatile("s_waitcnt lgkmcnt(0)\n\ts_barrier" ::: "memory");             \
    }

#define CCHUNK(CH_IDX)                                                              \
    {                                                                               \
        const float* cc = cq + (size_t)(CH_IDX) * CH * HID;                         \
        float d00 = cc[0*HID+i0], d01 = cc[0*HID+i1];                               \
        float d10 = cc[1*HID+i0], d11 = cc[1*HID+i1];                               \
        float d20 = cc[2*HID+i0], d21 = cc[2*HID+i1];                               \
        float d30 = cc[3*HID+i0], d31 = cc[3*HID+i1];                               \
        float d40 = cc[4*HID+i0], d41 = cc[4*HID+i1];                               \
        float d50 = cc[5*HID+i0], d51 = cc[5*HID+i1];                               \
        float d60 = cc[6*HID+i0], d61 = cc[6*HID+i1];                               \
        float d70 = cc[7*HID+i0], d71 = cc[7*HID+i1];                               \
        CSTEP(0, 1, d00, d01) CSTEP(1, 0, d10, d11)                                 \
        CSTEP(0, 1, d20, d21) CSTEP(1, 0, d30, d31)                                 \
        CSTEP(0, 1, d40, d41) CSTEP(1, 0, d50, d51)                                 \
        CSTEP(0, 1, d60, d61) CSTEP(1, 0, d70, d71)                                 \
    }

        for (int chp = 0; chp < NCHK / 2; ++chp) {
            WAITF(8 + b, chp + 1)
            CCHUNK(2 * chp)
            CCHUNK(2 * chp + 1)
            POSTF(16 + b, chp + 1)
        }
#undef CCHUNK
#undef CSTEP
    } else if (role <= 4) {
        // ---------------- D (role 3): tq;  E (role 4): tkT — 2 chunks/wait ----
        f16 (*stg)[HID] = smem.m.stg;
        const float* W = (role == 3) ? Wq : Wk;
        f16x8 bfW[8][2];
#pragma unroll
        for (int kt = 0; kt < 8; ++kt)
#pragma unroll
            for (int ct = 0; ct < 2; ++ct) {
                int n = wave * 32 + ct * 16 + lrow;
                const float* src = W + n * HID + kt * 32 + lkg * 8;
                f16x8 v;
#pragma unroll
                for (int e = 0; e < 8; ++e) v[e] = (f16)src[e];
                bfW[kt][ct] = v;
            }
        int col0 = wave * 32 + (lane & 15), col1 = col0 + 16;
        const float* hsb = Hs + (size_t)b * TT * HID;
        float* qb = Q + (size_t)b * TT * HID;

#define DEBODY(CH_IDX)                                                              \
    {                                                                               \
        int ch = (CH_IDX);                                                          \
        if (tid < 256) {                                                            \
            const float* src = hsb + (size_t)ch * CH * HID + tid * 8;               \
            float4 v0 = *(const float4*)&src[0];                                    \
            float4 v1 = *(const float4*)&src[4];                                    \
            f16x8 h = { (f16)v0.x, (f16)v0.y, (f16)v0.z, (f16)v0.w,                 \
                        (f16)v1.x, (f16)v1.y, (f16)v1.z, (f16)v1.w };               \
            *(f16x8*)((f16*)stg + tid * 8) = h;                                     \
        }                                                                           \
        __syncthreads();                                                            \
        if (lrow < 8) {                                                             \
            _Pragma("unroll")                                                       \
            for (int kt = 0; kt < 8; ++kt)                                          \
                a[kt] = *(const f16x8*)&stg[lrow][kt * 32 + lkg * 8];               \
        }                                                                           \
        f32x4 u0 = __builtin_amdgcn_mfma_f32_16x16x32_f16(a[0], bfW[0][0], Z, 0, 0, 0); \
        f32x4 u1 = __builtin_amdgcn_mfma_f32_16x16x32_f16(a[0], bfW[0][1], Z, 0, 0, 0); \
        _Pragma("unroll")                                                           \
        for (int kt = 1; kt < 8; ++kt) {                                            \
            u0 = __builtin_amdgcn_mfma_f32_16x16x32_f16(a[kt], bfW[kt][0], u0, 0, 0, 0); \
            u1 = __builtin_amdgcn_mfma_f32_16x16x32_f16(a[kt], bfW[kt][1], u1, 0, 0, 0); \
        }                                                                           \
        if (lane < 32) {                                                            \
            int tb2 = ch * CH + (lane >> 4) * 4;                                    \
            if (role == 3) {                                                        \
                float* co = qb + (size_t)tb2 * HID;                                 \
                co[0 * HID + col0] = fast_tanh(u0[0]);                              \
                co[1 * HID + col0] = fast_tanh(u0[1]);                              \
                co[2 * HID + col0] = fast_tanh(u0[2]);                              \
                co[3 * HID + col0] = fast_tanh(u0[3]);                              \
                co[0 * HID + col1] = fast_tanh(u1[0]);                              \
                co[1 * HID + col1] = fast_tanh(u1[1]);                              \
                co[2 * HID + col1] = fast_tanh(u1[2]);                              \
                co[3 * HID + col1] = fast_tanh(u1[3]);                              \
            } else {                                                                \
                float4 s0 = { fast_tanh(u0[0]), fast_tanh(u0[1]),                   \
                              fast_tanh(u0[2]), fast_tanh(u0[3]) };                 \
                float4 s1 = { fast_tanh(u1[0]), fast_tanh(u1[1]),                   \
                              fast_tanh(u1[2]), fast_tanh(u1[3]) };                 \
                *(float4*)&tkT[((size_t)b * HID + col0) * TT + tb2] = s0;           \
                *(float4*)&tkT[((size_t)b * HID + col1) * TT + tb2] = s1;           \
            }                                                                       \
        }                                                                           \
        __syncthreads();                                                            \
    }

        for (int chp = 0; chp < NCHK / 2; ++chp) {
            WAITF(16 + b, chp + 1)
            DEBODY(2 * chp + 0)
            DEBODY(2 * chp + 1)
            POSTF(24 + (role - 3) * 8 + b, chp + 1)
        }
#undef DEBODY
    } else {
        // ---------------- ATTN tile (blocks 40..551), R8-proven body ----------------
        int aidx = blockIdx.x - 40;
        int ab = aidx & 7;
        int t0 = (aidx >> 3) * TG;
        int p_need = (t0 + TG + 15) / 16;
        WAITF(24 + ab, p_need)   // tq ready through t0+TG
        WAITF(32 + ab, p_need)   // tkT ready through t0+TG

        float (*qs)[HID]     = smem.a.qs;
        float* vs            = smem.a.vs;
        float (*alpha)[HID]  = smem.a.alpha;
        float (*cvec)[8][68] = smem.a.cvec;
        float (*redm)[TG]    = smem.a.redm;
        float (*reds)[TG]    = smem.a.reds;
        const float* tq = Q;

        if (tid < HID) {
#pragma unroll
            for (int j = 0; j < TG; ++j)
                qs[j][tid] = tq[((size_t)ab * TT + t0 + j) * HID + tid];
            vs[tid] = vvec[tid];
        }
        __syncthreads();

        float sc[TG];
#pragma unroll
        for (int j = 0; j < TG; ++j) sc[j] = -1e30f;
        if ((wave << 6) < t0 + TG) {   // only waves 0..3 can pass -> tid < 256
            const float* kT = tkT + (size_t)ab * HID * TT + tid;
            float a0 = 0.f, a1 = 0.f, a2 = 0.f, a3 = 0.f;
            for (int jj = 0; jj < HID; jj += 4) {
                float k0 = kT[(size_t)(jj + 0) * TT];
                float k1 = kT[(size_t)(jj + 1) * TT];
                float k2 = kT[(size_t)(jj + 2) * TT];
                float k3 = kT[(size_t)(jj + 3) * TT];
                float4 vv = *(const float4*)&vs[jj];
                float4 q0 = *(const float4*)&qs[0][jj];
                float4 q1 = *(const float4*)&qs[1][jj];
                float4 q2 = *(const float4*)&qs[2][jj];
                float4 q3 = *(const float4*)&qs[3][jj];
#define TADD(qc, kc, vc, acc) { float num = qc + kc; float den = __builtin_fmaf(qc, kc, 1.f); acc += vc * num * __builtin_amdgcn_rcpf(den); }
                TADD(q0.x, k0, vv.x, a0) TADD(q0.y, k1, vv.y, a0) TADD(q0.z, k2, vv.z, a0) TADD(q0.w, k3, vv.w, a0)
                TADD(q1.x, k0, vv.x, a1) TADD(q1.y, k1, vv.y, a1) TADD(q1.z, k2, vv.z, a1) TADD(q1.w, k3, vv.w, a1)
                TADD(q2.x, k0, vv.x, a2) TADD(q2.y, k1, vv.y, a2) TADD(q2.z, k2, vv.z, a2) TADD(q2.w, k3, vv.w, a2)
                TADD(q3.x, k0, vv.x, a3) TADD(q3.y, k1, vv.y, a3) TADD(q3.z, k2, vv.z, a3) TADD(q3.w, k3, vv.w, a3)
#undef TADD
            }
            if (tid < t0 + 0) sc[0] = a0;
            if (tid < t0 + 1) sc[1] = a1;
            if (tid < t0 + 2) sc[2] = a2;
            if (tid < t0 + 3) sc[3] = a3;
        }
        float m0 = sc[0], m1 = sc[1], m2 = sc[2], m3 = sc[3];
#pragma unroll
        for (int off = 32; off; off >>= 1) {
            m0 = fmaxf(m0, __shfl_down(m0, off));
            m1 = fmaxf(m1, __shfl_down(m1, off));
            m2 = fmaxf(m2, __shfl_down(m2, off));
            m3 = fmaxf(m3, __shfl_down(m3, off));
        }
        if (lane == 0 && wave < 4) {
            redm[wave][0] = m0; redm[wave][1] = m1; redm[wave][2] = m2; redm[wave][3] = m3;
        }
        __syncthreads();
        float ej[TG];
#pragma unroll
        for (int j = 0; j < TG; ++j) {
            float m = fmaxf(fmaxf(redm[0][j], redm[1][j]), fmaxf(redm[2][j], redm[3][j]));
            ej[j] = (tid < t0 + j) ? exp2f((sc[j] - m) * 1.4426950408889634f) : 0.f;
        }
        float z0 = ej[0], z1 = ej[1], z2 = ej[2], z3 = ej[3];
#pragma unroll
        for (int off = 32; off; off >>= 1) {
            z0 += __shfl_down(z0, off);
            z1 += __shfl_down(z1, off);
            z2 += __shfl_down(z2, off);
            z3 += __shfl_down(z3, off);
        }
        if (lane == 0 && wave < 4) {
            reds[wave][0] = z0; reds[wave][1] = z1; reds[wave][2] = z2; reds[wave][3] = z3;
        }
        __syncthreads();
        if (tid < HID) {
#pragma unroll
            for (int j = 0; j < TG; ++j) {
                float z = reds[0][j] + reds[1][j] + reds[2][j] + reds[3][j];
                alpha[j][tid] = (t0 + j == 0) ? 0.f : ej[j] * __builtin_amdgcn_rcpf(z);
            }
        }
        __syncthreads();

        if (tid < HID) {
            float c0 = 0.f, c1 = 0.f, c2 = 0.f, c3 = 0.f;
            const float* hb = Hs + (size_t)ab * TT * HID;
            for (int s = 0; s < t0 + TG; s += 4) {
                float4 av0 = *(const float4*)&alpha[0][s];
                float4 av1 = *(const float4*)&alpha[1][s];
                float4 av2 = *(const float4*)&alpha[2][s];
                float4 av3 = *(const float4*)&alpha[3][s];
                float h0 = hb[(s + 0) * HID + tid];
                float h1 = hb[(s + 1) * HID + tid];
                float h2 = hb[(s + 2) * HID + tid];
                float h3 = hb[(s + 3) * HID + tid];
                c0 += av0.x * h0 + av0.y * h1 + av0.z * h2 + av0.w * h3;
                c1 += av1.x * h0 + av1.y * h1 + av1.z * h2 + av1.w * h3;
                c2 += av2.x * h0 + av2.y * h1 + av2.z * h2 + av2.w * h3;
                c3 += av3.x * h0 + av3.y * h1 + av3.z * h2 + av3.w * h3;
            }
            int ph = tid >> 6, jj = tid & 63;
            cvec[0][ph][jj] = hb[(size_t)(t0 + 0) * HID + tid]; cvec[0][4 + ph][jj] = c0;
            cvec[1][ph][jj] = hb[(size_t)(t0 + 1) * HID + tid]; cvec[1][4 + ph][jj] = c1;
            cvec[2][ph][jj] = hb[(size_t)(t0 + 2) * HID + tid]; cvec[2][4 + ph][jj] = c2;
            cvec[3][ph][jj] = hb[(size_t)(t0 + 3) * HID + tid]; cvec[3][4 + ph][jj] = c3;
        }
        __syncthreads();

        if (tid < VOCAB * 8) {
            int o = tid >> 3, p = tid & 7;
            const float* wr = Wfc + o * 2 * HID + p * 64;
#pragma unroll
            for (int j = 0; j < TG; ++j) {
                const float* cv = &cvec[j][p][0];
                float acc = 0.f;
                for (int jj = 0; jj < 64; jj += 4) {
                    float4 w  = *(const float4*)&wr[jj];
                    float4 cc = *(const float4*)&cv[jj];
                    acc += w.x * cc.x + w.y * cc.y + w.z * cc.z + w.w * cc.w;
                }
                acc += __shfl_down(acc, 4);
                acc += __shfl_down(acc, 2);
                acc += __shfl_down(acc, 1);
                if (p == 0) out[((size_t)ab * TT + t0 + j) * VOCAB + o] = acc + bfc[o];
            }
        }
    }
#undef WAITF
#undef POSTF
}

extern "C" void kernel_launch(void* const* d_in, const int* in_sizes, int n_in,
                              void* d_out, int out_size, void* d_ws, size_t ws_size,
                              hipStream_t stream)
{
    (void)in_sizes; (void)n_in; (void)out_size; (void)ws_size;
    const int*   x     = (const int*)d_in[0];
    const float* embed = (const float*)d_in[1];
    const float* Wih0  = (const float*)d_in[2];
    const float* bih0  = (const float*)d_in[3];
    const float* Whh0  = (const float*)d_in[4];
    const float* bhh0  = (const float*)d_in[5];
    const float* Wih1  = (const float*)d_in[6];
    const float* bih1  = (const float*)d_in[7];
    const float* Whh1  = (const float*)d_in[8];
    const float* bhh1  = (const float*)d_in[9];
    const float* Wq    = (const float*)d_in[10];
    const float* Wk    = (const float*)d_in[11];
    const float* vvec  = (const float*)d_in[12];
    const float* Wfc   = (const float*)d_in[13];
    const float* bfc   = (const float*)d_in[14];
    float* out = (float*)d_out;
    float* ws  = (float*)d_ws;

    const size_t SZ = (size_t)TT * BATCH * HID;  // 524288 floats = 2 MB
    float* C0  = ws;            // [t][b][i], produced by pre0
    float* Hs  = ws + SZ;       // [b][t][i] f32, produced by role C
    float* Q   = ws + 2 * SZ;   // [b][t] slots: h0(f16, stride 2*HID) -> C1(f32) -> tq(f32)
    float* tkT = ws + 3 * SZ;   // [b][i][t]

    pre0_kernel<<<256, 256, 0, stream>>>(x, embed, Wih0, bih0, bhh0, C0);
    mega_kernel<<<40 + BATCH * (TT / TG), 512, 0, stream>>>(
        Whh0, Wih1, Whh1, bih1, bhh1, Wq, Wk, C0, Q, Hs, tkT,
        vvec, Wfc, bfc, out);
}

// Round 19
// 209.291 us; speedup vs baseline: 1.4093x; 1.4093x over previous
//
#include <hip/hip_runtime.h>

#define HID   256
#define BATCH 8
#define TT    256   // time steps (SEQ-1)
#define SEQL  257
#define VOCAB 29
#define EMB   64
#define TG    4     // attn t-tile
#define CH    8     // pipeline chunk (steps)
#define NCHK  (TT / CH)

typedef _Float16 f16;
typedef f16  f16x8 __attribute__((ext_vector_type(8)));
typedef float f32x4 __attribute__((ext_vector_type(4)));

__device__ __forceinline__ float fast_tanh(float x) {
    float e = exp2f(x * 2.8853900817779268f);
    return 1.0f - 2.0f * __builtin_amdgcn_rcpf(1.0f + e);
}

// C0[t][b][i] = emb[x[b][t]] . W_ih0[i] + b_ih0[i] + b_hh0[i]; zero the pipe flags.
__global__ __launch_bounds__(256) void pre0_kernel(
    const int* __restrict__ x, const float* __restrict__ embed,
    const float* __restrict__ Wih0, const float* __restrict__ bih0,
    const float* __restrict__ bhh0, float* __restrict__ C0, int* __restrict__ flags)
{
    if (blockIdx.x == 0 && threadIdx.x < 32) flags[threadIdx.x] = 0;
    int b  = blockIdx.x & 7;
    int t0 = (blockIdx.x >> 3) * 8;
    int tid = threadIdx.x;
    __shared__ float er[8][EMB];
    for (int idx = tid; idx < 8 * EMB; idx += 256) {
        int tt = idx >> 6, j = idx & 63;
        er[tt][j] = embed[x[b * SEQL + t0 + tt] * EMB + j];
    }
    __syncthreads();
    int i = tid;
    float base = bih0[i] + bhh0[i];
    float acc[8];
#pragma unroll
    for (int tt = 0; tt < 8; ++tt) acc[tt] = base;
    const float* wr = Wih0 + i * EMB;
    for (int j = 0; j < EMB; j += 4) {
        float4 w = *(const float4*)&wr[j];
#pragma unroll
        for (int tt = 0; tt < 8; ++tt) {
            float4 h = *(const float4*)&er[tt][j];
            acc[tt] += h.x * w.x + h.y * w.y + h.z * w.z + h.w * w.w;
        }
    }
#pragma unroll
    for (int tt = 0; tt < 8; ++tt)
        C0[((t0 + tt) * BATCH + b) * HID + i] = acc[tt];
}

// 5-role chunk pipeline (R14 dataflow), uniform PAIR granularity + fence-free posts:
//  A: ungated; posts flags[b] per pair (16 posts)
//  B: 2 chunks per wait (16 waits on A-pairs, 16 pair posts)
//  C: 2 chunks per wait (16 waits on B-pairs), posts pairs (16)
//  D/E: 2 chunks per wait (16 waits on C-pairs)
// POSTF relies on release-store semantics (agent scope) -- no redundant threadfence.
__global__ __launch_bounds__(512) void mega_kernel(
    const float* __restrict__ Whh0, const float* __restrict__ Wih1,
    const float* __restrict__ Whh1, const float* __restrict__ bih1,
    const float* __restrict__ bhh1, const float* __restrict__ Wq,
    const float* __restrict__ Wk, const float* __restrict__ C0,
    float* __restrict__ Q, float* __restrict__ Hs,
    float* __restrict__ tkT, int* __restrict__ flags)
{
    __shared__ f16 hbuf[2][HID];
    __shared__ __align__(16) f16 stg[CH][HID];
    int tid = threadIdx.x;
    int wave = tid >> 6, lane = tid & 63;
    int lrow = lane & 15, lkg = lane >> 4;
    int role = blockIdx.x >> 3;
    int b = blockIdx.x & 7;
    int i0 = wave * 32 + lrow, i1 = i0 + 16;
    const f32x4 Z = {0.f, 0.f, 0.f, 0.f};

#define WAITF(idx, val)                                                             \
    {                                                                               \
        if (tid == 0) {                                                             \
            while (__hip_atomic_load(&flags[idx], __ATOMIC_ACQUIRE,                 \
                                     __HIP_MEMORY_SCOPE_AGENT) < (val))             \
                __builtin_amdgcn_s_sleep(2);                                        \
        }                                                                           \
        __syncthreads();                                                            \
    }
#define POSTF(idx, val)                                                             \
    {                                                                               \
        __syncthreads();                                                            \
        if (tid == 0) {                                                             \
            __hip_atomic_store(&flags[idx], (val), __ATOMIC_RELEASE,                \
                               __HIP_MEMORY_SCOPE_AGENT);                           \
        }                                                                           \
    }

    // persistent A-fragments: zero once; masked ds_reads only touch real rows
    f16x8 a[8];
#pragma unroll
    for (int kt = 0; kt < 8; ++kt)
#pragma unroll
        for (int e = 0; e < 8; ++e) a[kt][e] = (f16)0.f;

    if (role == 0) {
        // ---------------- A: layer 0 rec (ungated) ----------------
        for (int idx = tid; idx < 2 * HID; idx += 512) ((f16*)hbuf)[idx] = (f16)0.f;
        f16x8 bf[8][2];
#pragma unroll
        for (int kt = 0; kt < 8; ++kt)
#pragma unroll
            for (int ct = 0; ct < 2; ++ct) {
                int n = wave * 32 + ct * 16 + lrow;
                const float* src = Whh0 + n * HID + kt * 32 + lkg * 8;
                f16x8 v;
#pragma unroll
                for (int e = 0; e < 8; ++e) v[e] = (f16)src[e];
                bf[kt][ct] = v;
            }
        __syncthreads();
        const float* cp = C0 + b * HID;
        float c0 = cp[i0], c1 = cp[i1];
        cp += BATCH * HID;
        f16* hp = (f16*)(Q + (size_t)b * TT * HID);

#define ASTEP(CUR, NXT)                                                             \
    {                                                                               \
        float cn0 = cp[i0];                                                         \
        float cn1 = cp[i1];                                                         \
        cp += BATCH * HID;                                                          \
        if (lrow == 0) {                                                            \
            _Pragma("unroll")                                                       \
            for (int kt = 0; kt < 8; ++kt)                                          \
                a[kt] = *(const f16x8*)&hbuf[CUR][kt * 32 + lkg * 8];               \
        }                                                                           \
        f32x4 p00 = __builtin_amdgcn_mfma_f32_16x16x32_f16(a[0], bf[0][0], Z, 0, 0, 0); \
        f32x4 p01 = __builtin_amdgcn_mfma_f32_16x16x32_f16(a[0], bf[0][1], Z, 0, 0, 0); \
        f32x4 p10 = __builtin_amdgcn_mfma_f32_16x16x32_f16(a[2], bf[2][0], Z, 0, 0, 0); \
        f32x4 p11 = __builtin_amdgcn_mfma_f32_16x16x32_f16(a[2], bf[2][1], Z, 0, 0, 0); \
        f32x4 p20 = __builtin_amdgcn_mfma_f32_16x16x32_f16(a[4], bf[4][0], Z, 0, 0, 0); \
        f32x4 p21 = __builtin_amdgcn_mfma_f32_16x16x32_f16(a[4], bf[4][1], Z, 0, 0, 0); \
        f32x4 p30 = __builtin_amdgcn_mfma_f32_16x16x32_f16(a[6], bf[6][0], Z, 0, 0, 0); \
        f32x4 p31 = __builtin_amdgcn_mfma_f32_16x16x32_f16(a[6], bf[6][1], Z, 0, 0, 0); \
        p00 = __builtin_amdgcn_mfma_f32_16x16x32_f16(a[1], bf[1][0], p00, 0, 0, 0); \
        p01 = __builtin_amdgcn_mfma_f32_16x16x32_f16(a[1], bf[1][1], p01, 0, 0, 0); \
        p10 = __builtin_amdgcn_mfma_f32_16x16x32_f16(a[3], bf[3][0], p10, 0, 0, 0); \
        p11 = __builtin_amdgcn_mfma_f32_16x16x32_f16(a[3], bf[3][1], p11, 0, 0, 0); \
        p20 = __builtin_amdgcn_mfma_f32_16x16x32_f16(a[5], bf[5][0], p20, 0, 0, 0); \
        p21 = __builtin_amdgcn_mfma_f32_16x16x32_f16(a[5], bf[5][1], p21, 0, 0, 0); \
        p30 = __builtin_amdgcn_mfma_f32_16x16x32_f16(a[7], bf[7][0], p30, 0, 0, 0); \
        p31 = __builtin_amdgcn_mfma_f32_16x16x32_f16(a[7], bf[7][1], p31, 0, 0, 0); \
        float v0 = fast_tanh(((p00[0] + p10[0]) + (p20[0] + p30[0])) + c0);         \
        float v1 = fast_tanh(((p01[0] + p11[0]) + (p21[0] + p31[0])) + c1);         \
        f16 hv0 = (f16)v0, hv1 = (f16)v1;                                           \
        if (lane < 16) {                                                            \
            hbuf[NXT][i0] = hv0;                                                    \
            hbuf[NXT][i1] = hv1;                                                    \
            hp[i0] = hv0;                                                           \
            hp[i1] = hv1;                                                           \
        }                                                                           \
        hp += 2 * HID;   /* STRIDE 2*HID: keeps h0[t] clear of B's C1 overwrites */ \
        c0 = cn0; c1 = cn1;                                                         \
        asm volatile("s_waitcnt lgkmcnt(0)\n\ts_barrier" ::: "memory");             \
    }

        for (int ch = 0; ch < NCHK; ++ch) {
            ASTEP(0, 1) ASTEP(1, 0) ASTEP(0, 1) ASTEP(1, 0)
            ASTEP(0, 1) ASTEP(1, 0) ASTEP(0, 1) ASTEP(1, 0)
            if (ch & 1) POSTF(b, (ch + 1) >> 1)   // post pairs: 16 cheap posts
        }
#undef ASTEP
    } else if (role == 1) {
        // ---------------- B: C1 producer, 2 chunks per wait (pairs) ----------------
        f16x8 bfI[8][2];
#pragma unroll
        for (int kt = 0; kt < 8; ++kt)
#pragma unroll
            for (int ct = 0; ct < 2; ++ct) {
                int n = wave * 32 + ct * 16 + lrow;
                const float* src = Wih1 + n * HID + kt * 32 + lkg * 8;
                f16x8 v;
#pragma unroll
                for (int e = 0; e < 8; ++e) v[e] = (f16)src[e];
                bfI[kt][ct] = v;
            }
        int col0 = wave * 32 + (lane & 15), col1 = col0 + 16;
        float bv0 = bih1[col0] + bhh1[col0];
        float bv1 = bih1[col1] + bhh1[col1];
        float* qb = Q + (size_t)b * TT * HID;

#define BBODY(CH_IDX)                                                               \
    {                                                                               \
        int ch = (CH_IDX);                                                          \
        if (tid < 256) {                                                            \
            int tp = tid >> 5, seg = tid & 31;                                      \
            *(f16x8*)&stg[tp][seg * 8] =                                            \
                *(const f16x8*)((const f16*)(qb + (size_t)(ch * CH + tp) * HID) + seg * 8); \
        }                                                                           \
        __syncthreads();                                                            \
        if (lrow < 8) {                                                             \
            _Pragma("unroll")                                                       \
            for (int kt = 0; kt < 8; ++kt)                                          \
                a[kt] = *(const f16x8*)&stg[lrow][kt * 32 + lkg * 8];               \
        }                                                                           \
        f32x4 u0 = __builtin_amdgcn_mfma_f32_16x16x32_f16(a[0], bfI[0][0], Z, 0, 0, 0); \
        f32x4 u1 = __builtin_amdgcn_mfma_f32_16x16x32_f16(a[0], bfI[0][1], Z, 0, 0, 0); \
        _Pragma("unroll")                                                           \
        for (int kt = 1; kt < 8; ++kt) {                                            \
            u0 = __builtin_amdgcn_mfma_f32_16x16x32_f16(a[kt], bfI[kt][0], u0, 0, 0, 0); \
            u1 = __builtin_amdgcn_mfma_f32_16x16x32_f16(a[kt], bfI[kt][1], u1, 0, 0, 0); \
        }                                                                           \
        if (lane < 32) {                                                            \
            float* co = qb + (size_t)(ch * CH + (lane >> 4) * 4) * HID;             \
            co[0 * HID + col0] = u0[0] + bv0;                                       \
            co[1 * HID + col0] = u0[1] + bv0;                                       \
            co[2 * HID + col0] = u0[2] + bv0;                                       \
            co[3 * HID + col0] = u0[3] + bv0;                                       \
            co[0 * HID + col1] = u1[0] + bv1;                                       \
            co[1 * HID + col1] = u1[1] + bv1;                                       \
            co[2 * HID + col1] = u1[2] + bv1;                                       \
            co[3 * HID + col1] = u1[3] + bv1;                                       \
        }                                                                           \
    }

        for (int chp = 0; chp < NCHK / 2; ++chp) {
            WAITF(b, chp + 1)                 // A posts pairs
            BBODY(2 * chp)
            __syncthreads();                  // protect stg before restage
            BBODY(2 * chp + 1)
            POSTF(8 + b, chp + 1)             // 16 posts
        }
#undef BBODY
    } else if (role == 2) {
        // ---------------- C: layer 1 rec, 2 chunks per wait (pairs) ----------------
        for (int idx = tid; idx < 2 * HID; idx += 512) ((f16*)hbuf)[idx] = (f16)0.f;
        f16x8 bf[8][2];
#pragma unroll
        for (int kt = 0; kt < 8; ++kt)
#pragma unroll
            for (int ct = 0; ct < 2; ++ct) {
                int n = wave * 32 + ct * 16 + lrow;
                const float* src = Whh1 + n * HID + kt * 32 + lkg * 8;
                f16x8 v;
#pragma unroll
                for (int e = 0; e < 8; ++e) v[e] = (f16)src[e];
                bf[kt][ct] = v;
            }
        __syncthreads();
        float* ho = Hs + (size_t)b * TT * HID;
        const float* cq = Q + (size_t)b * TT * HID;

#define CSTEP(CUR, NXT, CV0, CV1)                                                   \
    {                                                                               \
        if (lrow == 0) {                                                            \
            _Pragma("unroll")                                                       \
            for (int kt = 0; kt < 8; ++kt)                                          \
                a[kt] = *(const f16x8*)&hbuf[CUR][kt * 32 + lkg * 8];               \
        }                                                                           \
        f32x4 p00 = __builtin_amdgcn_mfma_f32_16x16x32_f16(a[0], bf[0][0], Z, 0, 0, 0); \
        f32x4 p01 = __builtin_amdgcn_mfma_f32_16x16x32_f16(a[0], bf[0][1], Z, 0, 0, 0); \
        f32x4 p10 = __builtin_amdgcn_mfma_f32_16x16x32_f16(a[2], bf[2][0], Z, 0, 0, 0); \
        f32x4 p11 = __builtin_amdgcn_mfma_f32_16x16x32_f16(a[2], bf[2][1], Z, 0, 0, 0); \
        f32x4 p20 = __builtin_amdgcn_mfma_f32_16x16x32_f16(a[4], bf[4][0], Z, 0, 0, 0); \
        f32x4 p21 = __builtin_amdgcn_mfma_f32_16x16x32_f16(a[4], bf[4][1], Z, 0, 0, 0); \
        f32x4 p30 = __builtin_amdgcn_mfma_f32_16x16x32_f16(a[6], bf[6][0], Z, 0, 0, 0); \
        f32x4 p31 = __builtin_amdgcn_mfma_f32_16x16x32_f16(a[6], bf[6][1], Z, 0, 0, 0); \
        p00 = __builtin_amdgcn_mfma_f32_16x16x32_f16(a[1], bf[1][0], p00, 0, 0, 0); \
        p01 = __builtin_amdgcn_mfma_f32_16x16x32_f16(a[1], bf[1][1], p01, 0, 0, 0); \
        p10 = __builtin_amdgcn_mfma_f32_16x16x32_f16(a[3], bf[3][0], p10, 0, 0, 0); \
        p11 = __builtin_amdgcn_mfma_f32_16x16x32_f16(a[3], bf[3][1], p11, 0, 0, 0); \
        p20 = __builtin_amdgcn_mfma_f32_16x16x32_f16(a[5], bf[5][0], p20, 0, 0, 0); \
        p21 = __builtin_amdgcn_mfma_f32_16x16x32_f16(a[5], bf[5][1], p21, 0, 0, 0); \
        p30 = __builtin_amdgcn_mfma_f32_16x16x32_f16(a[7], bf[7][0], p30, 0, 0, 0); \
        p31 = __builtin_amdgcn_mfma_f32_16x16x32_f16(a[7], bf[7][1], p31, 0, 0, 0); \
        float v0 = fast_tanh(((p00[0] + p10[0]) + (p20[0] + p30[0])) + CV0);        \
        float v1 = fast_tanh(((p01[0] + p11[0]) + (p21[0] + p31[0])) + CV1);        \
        if (lane < 16) {                                                            \
            hbuf[NXT][i0] = (f16)v0;                                                \
            hbuf[NXT][i1] = (f16)v1;                                                \
            ho[i0] = v0;                                                            \
            ho[i1] = v1;                                                            \
        }                                                                           \
        ho += HID;                                                                  \
        asm volatile("s_waitcnt lgkmcnt(0)\n\ts_barrier" ::: "memory");             \
    }

#define CCHUNK(CH_IDX)                                                              \
    {                                                                               \
        const float* cc = cq + (size_t)(CH_IDX) * CH * HID;                         \
        float d00 = cc[0*HID+i0], d01 = cc[0*HID+i1];                               \
        float d10 = cc[1*HID+i0], d11 = cc[1*HID+i1];                               \
        float d20 = cc[2*HID+i0], d21 = cc[2*HID+i1];                               \
        float d30 = cc[3*HID+i0], d31 = cc[3*HID+i1];                               \
        float d40 = cc[4*HID+i0], d41 = cc[4*HID+i1];                               \
        float d50 = cc[5*HID+i0], d51 = cc[5*HID+i1];                               \
        float d60 = cc[6*HID+i0], d61 = cc[6*HID+i1];                               \
        float d70 = cc[7*HID+i0], d71 = cc[7*HID+i1];                               \
        CSTEP(0, 1, d00, d01) CSTEP(1, 0, d10, d11)                                 \
        CSTEP(0, 1, d20, d21) CSTEP(1, 0, d30, d31)                                 \
        CSTEP(0, 1, d40, d41) CSTEP(1, 0, d50, d51)                                 \
        CSTEP(0, 1, d60, d61) CSTEP(1, 0, d70, d71)                                 \
    }

        for (int chp = 0; chp < NCHK / 2; ++chp) {
            WAITF(8 + b, chp + 1)             // B posts pairs
            CCHUNK(2 * chp)
            CCHUNK(2 * chp + 1)
            POSTF(16 + b, chp + 1)            // post pairs: 16 cheap posts
        }
#undef CCHUNK
#undef CSTEP
    } else {
        // ---------------- D (role 3): tq;  E (role 4): tkT — 2 chunks per wait ----
        const float* W = (role == 3) ? Wq : Wk;
        f16x8 bfW[8][2];
#pragma unroll
        for (int kt = 0; kt < 8; ++kt)
#pragma unroll
            for (int ct = 0; ct < 2; ++ct) {
                int n = wave * 32 + ct * 16 + lrow;
                const float* src = W + n * HID + kt * 32 + lkg * 8;
                f16x8 v;
#pragma unroll
                for (int e = 0; e < 8; ++e) v[e] = (f16)src[e];
                bfW[kt][ct] = v;
            }
        int col0 = wave * 32 + (lane & 15), col1 = col0 + 16;
        const float* hsb = Hs + (size_t)b * TT * HID;
        float* qb = Q + (size_t)b * TT * HID;

#define DEBODY(CH_IDX)                                                              \
    {                                                                               \
        int ch = (CH_IDX);                                                          \
        if (tid < 256) {                                                            \
            const float* src = hsb + (size_t)ch * CH * HID + tid * 8;               \
            float4 v0 = *(const float4*)&src[0];                                    \
            float4 v1 = *(const float4*)&src[4];                                    \
            f16x8 h = { (f16)v0.x, (f16)v0.y, (f16)v0.z, (f16)v0.w,                 \
                        (f16)v1.x, (f16)v1.y, (f16)v1.z, (f16)v1.w };               \
            *(f16x8*)((f16*)stg + tid * 8) = h;                                     \
        }                                                                           \
        __syncthreads();                                                            \
        if (lrow < 8) {                                                             \
            _Pragma("unroll")                                                       \
            for (int kt = 0; kt < 8; ++kt)                                          \
                a[kt] = *(const f16x8*)&stg[lrow][kt * 32 + lkg * 8];               \
        }                                                                           \
        f32x4 u0 = __builtin_amdgcn_mfma_f32_16x16x32_f16(a[0], bfW[0][0], Z, 0, 0, 0); \
        f32x4 u1 = __builtin_amdgcn_mfma_f32_16x16x32_f16(a[0], bfW[0][1], Z, 0, 0, 0); \
        _Pragma("unroll")                                                           \
        for (int kt = 1; kt < 8; ++kt) {                                            \
            u0 = __builtin_amdgcn_mfma_f32_16x16x32_f16(a[kt], bfW[kt][0], u0, 0, 0, 0); \
            u1 = __builtin_amdgcn_mfma_f32_16x16x32_f16(a[kt], bfW[kt][1], u1, 0, 0, 0); \
        }                                                                           \
        if (lane < 32) {                                                            \
            int tb2 = ch * CH + (lane >> 4) * 4;                                    \
            if (role == 3) {                                                        \
                float* co = qb + (size_t)tb2 * HID;                                 \
                co[0 * HID + col0] = fast_tanh(u0[0]);                              \
                co[1 * HID + col0] = fast_tanh(u0[1]);                              \
                co[2 * HID + col0] = fast_tanh(u0[2]);                              \
                co[3 * HID + col0] = fast_tanh(u0[3]);                              \
                co[0 * HID + col1] = fast_tanh(u1[0]);                              \
                co[1 * HID + col1] = fast_tanh(u1[1]);                              \
                co[2 * HID + col1] = fast_tanh(u1[2]);                              \
                co[3 * HID + col1] = fast_tanh(u1[3]);                              \
            } else {                                                                \
                float4 s0 = { fast_tanh(u0[0]), fast_tanh(u0[1]),                   \
                              fast_tanh(u0[2]), fast_tanh(u0[3]) };                 \
                float4 s1 = { fast_tanh(u1[0]), fast_tanh(u1[1]),                   \
                              fast_tanh(u1[2]), fast_tanh(u1[3]) };                 \
                *(float4*)&tkT[((size_t)b * HID + col0) * TT + tb2] = s0;           \
                *(float4*)&tkT[((size_t)b * HID + col1) * TT + tb2] = s1;           \
            }                                                                       \
        }                                                                           \
        __syncthreads();                                                            \
    }

        for (int chp = 0; chp < NCHK / 2; ++chp) {
            WAITF(16 + b, chp + 1)            // C posts pairs
            DEBODY(2 * chp + 0)
            DEBODY(2 * chp + 1)
        }
#undef DEBODY
    }
#undef WAITF
#undef POSTF
}

// attn (R8-verified): tanh addition identity; batch pinned to XCD; padded cvec.
__global__ __launch_bounds__(256) void attn_kernel(
    const float* __restrict__ tq, const float* __restrict__ tkT,
    const float* __restrict__ vvec, const float* __restrict__ Hs,
    const float* __restrict__ Wfc, const float* __restrict__ bfc,
    float* __restrict__ out)
{
    int b  = blockIdx.x & 7;
    int t0 = (blockIdx.x >> 3) * TG;
    int tid = threadIdx.x;
    int wave = tid >> 6, lane = tid & 63;
    __shared__ float qs[TG][HID], vs[HID], alpha[TG][HID];
    __shared__ float cvec[TG][8][68];
    __shared__ float redm[4][TG], reds[4][TG];
#pragma unroll
    for (int j = 0; j < TG; ++j)
        qs[j][tid] = tq[((size_t)b * TT + t0 + j) * HID + tid];
    vs[tid] = vvec[tid];
    __syncthreads();

    float sc[TG];
#pragma unroll
    for (int j = 0; j < TG; ++j) sc[j] = -1e30f;
    if ((wave << 6) < t0 + TG) {
        const float* kT = tkT + (size_t)b * HID * TT + tid;
        float a0 = 0.f, a1 = 0.f, a2 = 0.f, a3 = 0.f;
        for (int jj = 0; jj < HID; jj += 4) {
            float k0 = kT[(size_t)(jj + 0) * TT];
            float k1 = kT[(size_t)(jj + 1) * TT];
            float k2 = kT[(size_t)(jj + 2) * TT];
            float k3 = kT[(size_t)(jj + 3) * TT];
            float4 vv = *(const float4*)&vs[jj];
            float4 q0 = *(const float4*)&qs[0][jj];
            float4 q1 = *(const float4*)&qs[1][jj];
            float4 q2 = *(const float4*)&qs[2][jj];
            float4 q3 = *(const float4*)&qs[3][jj];
#define TADD(qc, kc, vc, acc) { float num = qc + kc; float den = __builtin_fmaf(qc, kc, 1.f); acc += vc * num * __builtin_amdgcn_rcpf(den); }
            TADD(q0.x, k0, vv.x, a0) TADD(q0.y, k1, vv.y, a0) TADD(q0.z, k2, vv.z, a0) TADD(q0.w, k3, vv.w, a0)
            TADD(q1.x, k0, vv.x, a1) TADD(q1.y, k1, vv.y, a1) TADD(q1.z, k2, vv.z, a1) TADD(q1.w, k3, vv.w, a1)
            TADD(q2.x, k0, vv.x, a2) TADD(q2.y, k1, vv.y, a2) TADD(q2.z, k2, vv.z, a2) TADD(q2.w, k3, vv.w, a2)
            TADD(q3.x, k0, vv.x, a3) TADD(q3.y, k1, vv.y, a3) TADD(q3.z, k2, vv.z, a3) TADD(q3.w, k3, vv.w, a3)
#undef TADD
        }
        if (tid < t0 + 0) sc[0] = a0;
        if (tid < t0 + 1) sc[1] = a1;
        if (tid < t0 + 2) sc[2] = a2;
        if (tid < t0 + 3) sc[3] = a3;
    }
    float m0 = sc[0], m1 = sc[1], m2 = sc[2], m3 = sc[3];
#pragma unroll
    for (int off = 32; off; off >>= 1) {
        m0 = fmaxf(m0, __shfl_down(m0, off));
        m1 = fmaxf(m1, __shfl_down(m1, off));
        m2 = fmaxf(m2, __shfl_down(m2, off));
        m3 = fmaxf(m3, __shfl_down(m3, off));
    }
    if (lane == 0) { redm[wave][0] = m0; redm[wave][1] = m1; redm[wave][2] = m2; redm[wave][3] = m3; }
    __syncthreads();
    float ej[TG];
#pragma unroll
    for (int j = 0; j < TG; ++j) {
        float m = fmaxf(fmaxf(redm[0][j], redm[1][j]), fmaxf(redm[2][j], redm[3][j]));
        ej[j] = (tid < t0 + j) ? exp2f((sc[j] - m) * 1.4426950408889634f) : 0.f;
    }
    float z0 = ej[0], z1 = ej[1], z2 = ej[2], z3 = ej[3];
#pragma unroll
    for (int off = 32; off; off >>= 1) {
        z0 += __shfl_down(z0, off);
        z1 += __shfl_down(z1, off);
        z2 += __shfl_down(z2, off);
        z3 += __shfl_down(z3, off);
    }
    if (lane == 0) { reds[wave][0] = z0; reds[wave][1] = z1; reds[wave][2] = z2; reds[wave][3] = z3; }
    __syncthreads();
#pragma unroll
    for (int j = 0; j < TG; ++j) {
        float z = reds[0][j] + reds[1][j] + reds[2][j] + reds[3][j];
        alpha[j][tid] = (t0 + j == 0) ? 0.f : ej[j] * __builtin_amdgcn_rcpf(z);
    }
    __syncthreads();

    float c0 = 0.f, c1 = 0.f, c2 = 0.f, c3 = 0.f;
    const float* hb = Hs + (size_t)b * TT * HID;
    for (int s = 0; s < t0 + TG; s += 4) {
        float4 av0 = *(const float4*)&alpha[0][s];
        float4 av1 = *(const float4*)&alpha[1][s];
        float4 av2 = *(const float4*)&alpha[2][s];
        float4 av3 = *(const float4*)&alpha[3][s];
        float h0 = hb[(s + 0) * HID + tid];
        float h1 = hb[(s + 1) * HID + tid];
        float h2 = hb[(s + 2) * HID + tid];
        float h3 = hb[(s + 3) * HID + tid];
        c0 += av0.x * h0 + av0.y * h1 + av0.z * h2 + av0.w * h3;
        c1 += av1.x * h0 + av1.y * h1 + av1.z * h2 + av1.w * h3;
        c2 += av2.x * h0 + av2.y * h1 + av2.z * h2 + av2.w * h3;
        c3 += av3.x * h0 + av3.y * h1 + av3.z * h2 + av3.w * h3;
    }
    {
        int ph = tid >> 6, jj = tid & 63;
        cvec[0][ph][jj] = hb[(size_t)(t0 + 0) * HID + tid]; cvec[0][4 + ph][jj] = c0;
        cvec[1][ph][jj] = hb[(size_t)(t0 + 1) * HID + tid]; cvec[1][4 + ph][jj] = c1;
        cvec[2][ph][jj] = hb[(size_t)(t0 + 2) * HID + tid]; cvec[2][4 + ph][jj] = c2;
        cvec[3][ph][jj] = hb[(size_t)(t0 + 3) * HID + tid]; cvec[3][4 + ph][jj] = c3;
    }
    __syncthreads();

    if (tid < VOCAB * 8) {
        int o = tid >> 3, p = tid & 7;
        const float* wr = Wfc + o * 2 * HID + p * 64;
#pragma unroll
        for (int j = 0; j < TG; ++j) {
            const float* cv = &cvec[j][p][0];
            float a = 0.f;
            for (int jj = 0; jj < 64; jj += 4) {
                float4 w  = *(const float4*)&wr[jj];
                float4 cc = *(const float4*)&cv[jj];
                a += w.x * cc.x + w.y * cc.y + w.z * cc.z + w.w * cc.w;
            }
            a += __shfl_down(a, 4);
            a += __shfl_down(a, 2);
            a += __shfl_down(a, 1);
            if (p == 0) out[((size_t)b * TT + t0 + j) * VOCAB + o] = a + bfc[o];
        }
    }
}

extern "C" void kernel_launch(void* const* d_in, const int* in_sizes, int n_in,
                              void* d_out, int out_size, void* d_ws, size_t ws_size,
                              hipStream_t stream)
{
    (void)in_sizes; (void)n_in; (void)out_size; (void)ws_size;
    const int*   x     = (const int*)d_in[0];
    const float* embed = (const float*)d_in[1];
    const float* Wih0  = (const float*)d_in[2];
    const float* bih0  = (const float*)d_in[3];
    const float* Whh0  = (const float*)d_in[4];
    const float* bhh0  = (const float*)d_in[5];
    const float* Wih1  = (const float*)d_in[6];
    const float* bih1  = (const float*)d_in[7];
    const float* Whh1  = (const float*)d_in[8];
    const float* bhh1  = (const float*)d_in[9];
    const float* Wq    = (const float*)d_in[10];
    const float* Wk    = (const float*)d_in[11];
    const float* vvec  = (const float*)d_in[12];
    const float* Wfc   = (const float*)d_in[13];
    const float* bfc   = (const float*)d_in[14];
    float* out = (float*)d_out;
    float* ws  = (float*)d_ws;

    const size_t SZ = (size_t)TT * BATCH * HID;  // 524288 floats = 2 MB
    float* C0  = ws;            // [t][b][i], produced by pre0
    float* Hs  = ws + SZ;       // [b][t][i] f32, produced by role C
    float* Q   = ws + 2 * SZ;   // [b][t] slots: h0(f16, stride 2*HID) -> C1(f32) -> tq(f32)
    float* tkT = ws + 3 * SZ;   // [b][i][t]
    int* flags = (int*)d_out;   // 32 ints; zeroed by pre0; overwritten by attn

    pre0_kernel<<<256, 256, 0, stream>>>(x, embed, Wih0, bih0, bhh0, C0, flags);
    mega_kernel<<<40, 512, 0, stream>>>(Whh0, Wih1, Whh1, bih1, bhh1, Wq, Wk,
                                        C0, Q, Hs, tkT, flags);
    attn_kernel<<<512, 256, 0, stream>>>(Q, tkT, vvec, Hs, Wfc, bfc, out);
}